// Round 2
// baseline (434.103 us; speedup 1.0000x reference)
//
#include <hip/hip_runtime.h>

#define EPS 1e-4f
#define FRAMES 4000
#define EPT 16              // elements per thread
#define ACTIVE 250          // 250 * 16 = 4000

// One block (256 threads) per row. Thread t owns contiguous elements
// [16t, 16t+16). Single scan pass: per-thread serial scan -> wave scan of
// thread totals -> 4-entry cross-wave LDS scan -> normalize from registers.
__global__ __launch_bounds__(256) void cumnorm_kernel(const float* __restrict__ x,
                                                      float* __restrict__ out) {
    const int row  = blockIdx.x;
    const int t    = threadIdx.x;
    const int lane = t & 63;
    const int wave = t >> 6;

    __shared__ float wave_s[4];
    __shared__ float wave_q[4];

    const float* __restrict__ xr  = x   + (size_t)row * FRAMES;
    float*       __restrict__ outr = out + (size_t)row * FRAMES;

    const bool active = (t < ACTIVE);

    // ---- load 16 contiguous elements (4 x float4, independent loads) ----
    float v[EPT];
    if (active) {
        const float4* xp = (const float4*)(xr + t * EPT);
        float4 a = xp[0], b = xp[1], c = xp[2], d = xp[3];
        v[0]=a.x;  v[1]=a.y;  v[2]=a.z;  v[3]=a.w;
        v[4]=b.x;  v[5]=b.y;  v[6]=b.z;  v[7]=b.w;
        v[8]=c.x;  v[9]=c.y;  v[10]=c.z; v[11]=c.w;
        v[12]=d.x; v[13]=d.y; v[14]=d.z; v[15]=d.w;
    } else {
        #pragma unroll
        for (int j = 0; j < EPT; ++j) v[j] = 0.0f;
    }

    // ---- per-thread totals ----
    float ts = 0.0f, tq = 0.0f;
    #pragma unroll
    for (int j = 0; j < EPT; ++j) { ts += v[j]; tq = fmaf(v[j], v[j], tq); }

    // ---- wave-inclusive scan of (ts, tq) across 64 lanes ----
    float ss = ts, qq = tq;
    #pragma unroll
    for (int d = 1; d < 64; d <<= 1) {
        float us = __shfl_up(ss, d, 64);
        float uq = __shfl_up(qq, d, 64);
        if (lane >= d) { ss += us; qq += uq; }
    }

    // ---- cross-wave: publish wave totals, each thread sums waves before it ----
    if (lane == 63) { wave_s[wave] = ss; wave_q[wave] = qq; }
    __syncthreads();
    float base_s = 0.0f, base_q = 0.0f;
    #pragma unroll
    for (int w = 0; w < 3; ++w) {
        if (w < wave) { base_s += wave_s[w]; base_q += wave_q[w]; }
    }

    // ---- exclusive prefix for this thread's segment ----
    const float excl_s = base_s + (ss - ts);
    const float excl_q = base_q + (qq - tq);

    // ---- normalize: re-scan serially, write 4 x float4 ----
    if (active) {
        float cs = excl_s, cq = excl_q;
        const float cnt0 = (float)(t * EPT);
        float4* op = (float4*)(outr + t * EPT);
        #pragma unroll
        for (int g = 0; g < 4; ++g) {
            float4 r;
            float* rp = (float*)&r;
            #pragma unroll
            for (int k = 0; k < 4; ++k) {
                const int j = g * 4 + k;
                cs += v[j];
                cq = fmaf(v[j], v[j], cq);
                const float inv  = __builtin_amdgcn_rcpf(cnt0 + (float)(j + 1));
                const float mean = cs * inv;
                const float var  = fmaf(-mean, mean, cq * inv);
                rp[k] = (v[j] - mean) * __builtin_amdgcn_rsqf(var + EPS);
            }
            op[g] = r;
        }
    }
}

extern "C" void kernel_launch(void* const* d_in, const int* in_sizes, int n_in,
                              void* d_out, int out_size, void* d_ws, size_t ws_size,
                              hipStream_t stream) {
    const float* x = (const float*)d_in[0];
    float* out = (float*)d_out;
    const int rows = in_sizes[0] / FRAMES;  // 32*512 = 16384

    cumnorm_kernel<<<rows, 256, 0, stream>>>(x, out);
}